// Round 1
// baseline (198.690 us; speedup 1.0000x reference)
//
#include <hip/hip_runtime.h>

// CAN: per-sample 2-layer MLP, B=16384, N=50, D=16.
// x (N,D) -> relu(x@W0+b0) -> relu(.@W1+b1), params packed per sample:
// [W0: 256][b0: 16][W1: 256][b1: 16] = 544 floats.
//
// Strategy: 1 wave per sample; lanes 0..49 each own one row of x.
// Params are wave-uniform -> force pointer uniform via readfirstlane so the
// compiler emits s_load (SMEM) for all W/b accesses; inner loops are
// v_fmac_f32 with SGPR W operand. No LDS needed.

#define CAN_D 16
#define CAN_N 50
#define CAN_PSTRIDE 544   // D*(D+1)*2
#define SAMPLES_PER_BLOCK 4

__global__ __launch_bounds__(256) void can_kernel(
    const float* __restrict__ user_emb,
    const float* __restrict__ item_emb,
    float* __restrict__ out,
    int B)
{
    const int wave = threadIdx.x >> 6;
    const int lane = threadIdx.x & 63;
    const int s = blockIdx.x * SAMPLES_PER_BLOCK + wave;
    if (s >= B) return;

    // Wave-uniform parameter pointer, forced into SGPRs so W/b loads become
    // scalar (SMEM) loads — W is broadcast to all lanes via SGPR operand.
    uint64_t pbase = (uint64_t)(item_emb + (size_t)s * CAN_PSTRIDE);
    uint32_t plo = __builtin_amdgcn_readfirstlane((uint32_t)pbase);
    uint32_t phi = __builtin_amdgcn_readfirstlane((uint32_t)(pbase >> 32));
    const float* __restrict__ P = (const float*)(((uint64_t)phi << 32) | plo);

    if (lane >= CAN_N) return;

    // Load this lane's row of x: 16 floats = 4x float4 (64B per lane).
    const float4* __restrict__ x4 =
        (const float4*)(user_emb + ((size_t)s * CAN_N + lane) * CAN_D);
    float4 v0 = x4[0], v1 = x4[1], v2 = x4[2], v3 = x4[3];

    float x[CAN_D];
    x[ 0]=v0.x; x[ 1]=v0.y; x[ 2]=v0.z; x[ 3]=v0.w;
    x[ 4]=v1.x; x[ 5]=v1.y; x[ 6]=v1.z; x[ 7]=v1.w;
    x[ 8]=v2.x; x[ 9]=v2.y; x[10]=v2.z; x[11]=v2.w;
    x[12]=v3.x; x[13]=v3.y; x[14]=v3.z; x[15]=v3.w;

    float y[CAN_D];

    // ---- Layer 0: y = relu(x @ W0 + b0); W0 = P[0..255], b0 = P[256..271]
#pragma unroll
    for (int e = 0; e < CAN_D; ++e) y[e] = P[CAN_D * CAN_D + e];
#pragma unroll
    for (int d = 0; d < CAN_D; ++d) {
#pragma unroll
        for (int e = 0; e < CAN_D; ++e) {
            y[e] = fmaf(x[d], P[d * CAN_D + e], y[e]);
        }
    }
#pragma unroll
    for (int e = 0; e < CAN_D; ++e) y[e] = fmaxf(y[e], 0.0f);

    // ---- Layer 1: x = relu(y @ W1 + b1); W1 = P[272..527], b1 = P[528..543]
#pragma unroll
    for (int e = 0; e < CAN_D; ++e) x[e] = P[272 + CAN_D * CAN_D + e];
#pragma unroll
    for (int d = 0; d < CAN_D; ++d) {
#pragma unroll
        for (int e = 0; e < CAN_D; ++e) {
            x[e] = fmaf(y[d], P[272 + d * CAN_D + e], x[e]);
        }
    }
#pragma unroll
    for (int e = 0; e < CAN_D; ++e) x[e] = fmaxf(x[e], 0.0f);

    // ---- Store row (4x float4)
    float4* __restrict__ o4 =
        (float4*)(out + ((size_t)s * CAN_N + lane) * CAN_D);
    o4[0] = make_float4(x[ 0], x[ 1], x[ 2], x[ 3]);
    o4[1] = make_float4(x[ 4], x[ 5], x[ 6], x[ 7]);
    o4[2] = make_float4(x[ 8], x[ 9], x[10], x[11]);
    o4[3] = make_float4(x[12], x[13], x[14], x[15]);
}

extern "C" void kernel_launch(void* const* d_in, const int* in_sizes, int n_in,
                              void* d_out, int out_size, void* d_ws, size_t ws_size,
                              hipStream_t stream) {
    const float* user_emb = (const float*)d_in[0];
    const float* item_emb = (const float*)d_in[1];
    float* out = (float*)d_out;

    const int B = in_sizes[0] / (CAN_N * CAN_D);   // 16384
    const int blocks = (B + SAMPLES_PER_BLOCK - 1) / SAMPLES_PER_BLOCK;
    can_kernel<<<blocks, 256, 0, stream>>>(user_emb, item_emb, out, B);
}

// Round 2
// 157.589 us; speedup vs baseline: 1.2608x; 1.2608x over previous
//
#include <hip/hip_runtime.h>

// CAN: per-sample 2-layer MLP, B=16384, N=50, D=16.
// x (N,D) -> relu(x@W0+b0) -> relu(.@W1+b1), params packed per sample:
// [W0: 256][b0: 16][W1: 256][b1: 16] = 544 floats.
//
// R2 strategy: 1 wave per sample; lanes 0..49 own rows of x.
// Params staged with 3 wide coalesced vector loads (high MLP), then
// broadcast to all lanes via v_readlane -> SGPR -> scalar operand of
// v_fmac_f32. No LDS, no per-lane replication of W through memory.

#define CAN_D 16
#define CAN_N 50
#define CAN_PSTRIDE 544   // D*(D+1)*2
#define SAMPLES_PER_BLOCK 4

__device__ __forceinline__ float rdlane(float v, int srclane) {
    return __builtin_bit_cast(float,
        __builtin_amdgcn_readlane(__builtin_bit_cast(int, v), srclane));
}

__device__ __forceinline__ float f4c(const float4& v, int c) {
    switch (c) {                 // c is compile-time under full unroll
        case 0: return v.x;
        case 1: return v.y;
        case 2: return v.z;
        default: return v.w;
    }
}

// param j of this sample, broadcast from the lane that staged it.
// p0: params[4*lane + c]        for j in [0,256)
// p1: params[256 + 4*lane + c]  for j in [256,512)
// p2: params[512 + lane]        for j in [512,544), lanes 0..31
__device__ __forceinline__ float getp(const float4& p0, const float4& p1,
                                      float p2, int j) {
    if (j < 256)      return rdlane(f4c(p0, j & 3), j >> 2);
    else if (j < 512) return rdlane(f4c(p1, (j - 256) & 3), (j - 256) >> 2);
    else              return rdlane(p2, j - 512);
}

__global__ __launch_bounds__(256) void can_kernel(
    const float* __restrict__ user_emb,
    const float* __restrict__ item_emb,
    float* __restrict__ out,
    int B)
{
    const int wave = threadIdx.x >> 6;
    const int lane = threadIdx.x & 63;
    const int s = blockIdx.x * SAMPLES_PER_BLOCK + wave;
    if (s >= B) return;   // wave-uniform

    // ---- Stage params: 2x float4 + 1 dword per lane, all coalesced.
    const float* __restrict__ P = item_emb + (size_t)s * CAN_PSTRIDE;
    const float4* __restrict__ P4 = (const float4*)P;
    float4 p0 = P4[lane];        // params [4*lane .. 4*lane+3]
    float4 p1 = P4[64 + lane];   // params [256+4*lane .. ]
    float  p2 = (lane < 32) ? P[512 + lane] : 0.0f;  // params [512+lane]

    // ---- Load this lane's row of x (clamped for lanes >= N; discarded).
    const int row = (lane < CAN_N) ? lane : 0;
    const float4* __restrict__ x4 =
        (const float4*)(user_emb + ((size_t)s * CAN_N + row) * CAN_D);
    float4 v0 = x4[0], v1 = x4[1], v2 = x4[2], v3 = x4[3];

    float x[CAN_D];
    x[ 0]=v0.x; x[ 1]=v0.y; x[ 2]=v0.z; x[ 3]=v0.w;
    x[ 4]=v1.x; x[ 5]=v1.y; x[ 6]=v1.z; x[ 7]=v1.w;
    x[ 8]=v2.x; x[ 9]=v2.y; x[10]=v2.z; x[11]=v2.w;
    x[12]=v3.x; x[13]=v3.y; x[14]=v3.z; x[15]=v3.w;

    float y[CAN_D];

    // ---- Layer 0: y = relu(x @ W0 + b0); W0 = P[0..255], b0 = P[256..271]
#pragma unroll
    for (int e = 0; e < CAN_D; ++e) y[e] = getp(p0, p1, p2, 256 + e);
#pragma unroll
    for (int d = 0; d < CAN_D; ++d) {
#pragma unroll
        for (int e = 0; e < CAN_D; ++e) {
            y[e] = fmaf(x[d], getp(p0, p1, p2, d * CAN_D + e), y[e]);
        }
    }
#pragma unroll
    for (int e = 0; e < CAN_D; ++e) y[e] = fmaxf(y[e], 0.0f);

    // ---- Layer 1: x = relu(y @ W1 + b1); W1 = P[272..527], b1 = P[528..543]
#pragma unroll
    for (int e = 0; e < CAN_D; ++e) x[e] = getp(p0, p1, p2, 528 + e);
#pragma unroll
    for (int d = 0; d < CAN_D; ++d) {
#pragma unroll
        for (int e = 0; e < CAN_D; ++e) {
            x[e] = fmaf(y[d], getp(p0, p1, p2, 272 + d * CAN_D + e), x[e]);
        }
    }
#pragma unroll
    for (int e = 0; e < CAN_D; ++e) x[e] = fmaxf(x[e], 0.0f);

    // ---- Store row (4x float4), lanes 0..49 only.
    if (lane < CAN_N) {
        float4* __restrict__ o4 =
            (float4*)(out + ((size_t)s * CAN_N + lane) * CAN_D);
        o4[0] = make_float4(x[ 0], x[ 1], x[ 2], x[ 3]);
        o4[1] = make_float4(x[ 4], x[ 5], x[ 6], x[ 7]);
        o4[2] = make_float4(x[ 8], x[ 9], x[10], x[11]);
        o4[3] = make_float4(x[12], x[13], x[14], x[15]);
    }
}

extern "C" void kernel_launch(void* const* d_in, const int* in_sizes, int n_in,
                              void* d_out, int out_size, void* d_ws, size_t ws_size,
                              hipStream_t stream) {
    const float* user_emb = (const float*)d_in[0];
    const float* item_emb = (const float*)d_in[1];
    float* out = (float*)d_out;

    const int B = in_sizes[0] / (CAN_N * CAN_D);   // 16384
    const int blocks = (B + SAMPLES_PER_BLOCK - 1) / SAMPLES_PER_BLOCK;
    can_kernel<<<blocks, 256, 0, stream>>>(user_emb, item_emb, out, B);
}

// Round 3
// 127.413 us; speedup vs baseline: 1.5594x; 1.2368x over previous
//
#include <hip/hip_runtime.h>

// CAN: per-sample 2-layer MLP, B=16384, N=50, D=16.
// R3: MFMA path. 1 wave = 1 sample. v_mfma_f32_16x16x32_bf16, K padded 16->32.
//   A-frag (x rows) loaded straight from global in MFMA layout (2x float4/lane,
//   quads 0-1 only; quads 2-3 zero). B-frag (W) loaded coalesced, no broadcast.
//   Inter-layer transpose via wave-private LDS round-trip (no __syncthreads).
//   fp32->bf16 RNE bit-trick; accumulate fp32 in C.

#define CAN_D 16
#define CAN_N 50
#define CAN_PSTRIDE 544     // D*(D+1)*2
#define WAVES_PER_BLOCK 4
#define YSTRIDE 20          // LDS row stride in floats: 80B rows, 16B-aligned,
                            // breaks pow2 bank pattern

typedef __attribute__((ext_vector_type(8))) short short8;   // 8 bf16 (4 VGPRs)
typedef __attribute__((ext_vector_type(4))) float f32x4;

union ABFrag { int i[4]; short8 v; };

// round-to-nearest-even fp32->bf16, pack two into one dword (lo in [15:0])
__device__ __forceinline__ int pack2_bf16(float lo, float hi) {
    unsigned a = __builtin_bit_cast(unsigned, lo);
    unsigned b = __builtin_bit_cast(unsigned, hi);
    a = (a + 0x7FFFu + ((a >> 16) & 1u)) >> 16;
    b = (b + 0x7FFFu + ((b >> 16) & 1u)) & 0xFFFF0000u;
    return (int)(a | b);
}

__global__ __launch_bounds__(256) void can_kernel(
    const float* __restrict__ user_emb,
    const float* __restrict__ item_emb,
    float* __restrict__ out, int B)
{
    __shared__ __align__(16) float ybuf[WAVES_PER_BLOCK][4][16 * YSTRIDE];

    const int wave = threadIdx.x >> 6;
    const int lane = threadIdx.x & 63;
    const int s = blockIdx.x * WAVES_PER_BLOCK + wave;
    if (s >= B) return;                 // wave-uniform

    const int n    = lane & 15;         // MFMA col (and A row index)
    const int quad = lane >> 4;

    const float* __restrict__ P = item_emb + (size_t)s * CAN_PSTRIDE;

    // ---- B fragments: W0 = P[0..255], W1 = P[272..527].
    // B layout: lane holds B[k = quad*8 + j][n], j=0..7. quads 2,3 -> k>=16 -> 0.
    ABFrag w0, w1;
    if (quad < 2) {
        const float* W0 = P + quad * 8 * CAN_D + n;
        const float* W1 = P + 272 + quad * 8 * CAN_D + n;
        float t0[8], t1[8];
#pragma unroll
        for (int j = 0; j < 8; ++j) { t0[j] = W0[j * CAN_D]; t1[j] = W1[j * CAN_D]; }
#pragma unroll
        for (int j = 0; j < 4; ++j) {
            w0.i[j] = pack2_bf16(t0[2 * j], t0[2 * j + 1]);
            w1.i[j] = pack2_bf16(t1[2 * j], t1[2 * j + 1]);
        }
    } else {
#pragma unroll
        for (int j = 0; j < 4; ++j) { w0.i[j] = 0; w1.i[j] = 0; }
    }
    const float b0 = P[256 + n];   // bias: C init, col n, all rows
    const float b1 = P[528 + n];

    const float* __restrict__ xbase = user_emb + (size_t)s * (CAN_N * CAN_D);

#pragma unroll
    for (int t = 0; t < 4; ++t) {
        // ---- layer-0 A fragment straight from global:
        // lane needs x[t*16 + n][quad*8 .. quad*8+7] = 2x float4 (quads 0,1).
        ABFrag a0;
        if (quad < 2) {
            int row = t * 16 + n;
            if (row > CAN_N - 1) row = CAN_N - 1;   // clamp (tile 3), masked at store
            const float4* px = (const float4*)(xbase + row * CAN_D + quad * 8);
            float4 u0 = px[0], u1 = px[1];
            a0.i[0] = pack2_bf16(u0.x, u0.y);
            a0.i[1] = pack2_bf16(u0.z, u0.w);
            a0.i[2] = pack2_bf16(u1.x, u1.y);
            a0.i[3] = pack2_bf16(u1.z, u1.w);
        } else {
#pragma unroll
            for (int j = 0; j < 4; ++j) a0.i[j] = 0;
        }

        f32x4 c0 = {b0, b0, b0, b0};
        c0 = __builtin_amdgcn_mfma_f32_16x16x32_bf16(a0.v, w0.v, c0, 0, 0, 0);

        // ---- relu + C-layout -> LDS (row-major, stride YSTRIDE)
        float* yb = &ybuf[wave][t][0];
#pragma unroll
        for (int r = 0; r < 4; ++r)
            yb[(quad * 4 + r) * YSTRIDE + n] = fmaxf(c0[r], 0.0f);

        // ---- layer-1 A fragment: read back in A layout (8 consecutive floats)
        ABFrag a1;
        if (quad < 2) {
            const float* pr = yb + n * YSTRIDE + quad * 8;  // 16B aligned
            float4 v0 = *(const float4*)pr;
            float4 v1 = *(const float4*)(pr + 4);
            a1.i[0] = pack2_bf16(v0.x, v0.y);
            a1.i[1] = pack2_bf16(v0.z, v0.w);
            a1.i[2] = pack2_bf16(v1.x, v1.y);
            a1.i[3] = pack2_bf16(v1.z, v1.w);
        } else {
#pragma unroll
            for (int j = 0; j < 4; ++j) a1.i[j] = 0;
        }

        f32x4 c1 = {b1, b1, b1, b1};
        c1 = __builtin_amdgcn_mfma_f32_16x16x32_bf16(a1.v, w1.v, c1, 0, 0, 0);

        // ---- relu + store (C layout: row = t*16 + quad*4 + r, col = n)
#pragma unroll
        for (int r = 0; r < 4; ++r) {
            int grow = t * 16 + quad * 4 + r;
            if (grow < CAN_N)
                out[((size_t)s * CAN_N + grow) * CAN_D + n] = fmaxf(c1[r], 0.0f);
        }
    }
}

extern "C" void kernel_launch(void* const* d_in, const int* in_sizes, int n_in,
                              void* d_out, int out_size, void* d_ws, size_t ws_size,
                              hipStream_t stream) {
    const float* user_emb = (const float*)d_in[0];
    const float* item_emb = (const float*)d_in[1];
    float* out = (float*)d_out;

    const int B = in_sizes[0] / (CAN_N * CAN_D);   // 16384
    const int blocks = (B + WAVES_PER_BLOCK - 1) / WAVES_PER_BLOCK;
    can_kernel<<<blocks, 256, 0, stream>>>(user_emb, item_emb, out, B);
}

// Round 5
// 126.477 us; speedup vs baseline: 1.5710x; 1.0074x over previous
//
#include <hip/hip_runtime.h>

// CAN: per-sample 2-layer MLP, B=16384, N=50, D=16.
// R5 = R4 structure with compile-safe bf16 packing (__bf16 casts; ROCm 7.2
// has no __floats2bfloat162_rn).
//   - ALL global loads issued up front (x tiles, W0/W1 strided, biases)
//     -> one latency exposure per wave, ~26 VMEM in flight.
//   - bf16 packing via native __bf16 casts (RNE, ~3 inst/pair).
//   - LDS ping-pong (2 tile buffers/wave, 10KB/block) so LDS never caps
//     occupancy; same buffer reused for the c1 -> float4-store transpose.
//   - Coalesced global stores: 4x global_store_dwordx4 per tile via LDS
//     transpose instead of 16 masked dword stores.

#define CAN_D 16
#define CAN_N 50
#define CAN_PSTRIDE 544     // D*(D+1)*2
#define WAVES_PER_BLOCK 4
#define YSTRIDE 20          // floats per LDS row: mult of 4 (16B-aligned b128),
                            // non-pow2 -> <=2-way banks (free)

typedef __attribute__((ext_vector_type(8))) short short8;   // 8 bf16
typedef __attribute__((ext_vector_type(4))) float f32x4;

union ABFrag { int i[4]; short8 v; };

// RNE fp32->bf16 via native __bf16 casts; lo -> bits [15:0].
__device__ __forceinline__ int pack2(float lo, float hi) {
    unsigned short ua = __builtin_bit_cast(unsigned short, (__bf16)lo);
    unsigned short ub = __builtin_bit_cast(unsigned short, (__bf16)hi);
    return (int)((unsigned)ua | ((unsigned)ub << 16));
}

__global__ __launch_bounds__(256, 5) void can_kernel(
    const float* __restrict__ user_emb,
    const float* __restrict__ item_emb,
    float* __restrict__ out, int B)
{
    __shared__ __align__(16) float ybuf[WAVES_PER_BLOCK][2][16 * YSTRIDE];

    const int wave = threadIdx.x >> 6;
    const int lane = threadIdx.x & 63;
    const int s = blockIdx.x * WAVES_PER_BLOCK + wave;
    if (s >= B) return;                 // wave-uniform

    const int n    = lane & 15;         // MFMA col
    const int quad = lane >> 4;

    const float* __restrict__ P     = item_emb + (size_t)s * CAN_PSTRIDE;
    const float* __restrict__ xbase = user_emb + (size_t)s * (CAN_N * CAN_D);
    float* __restrict__ obase       = out      + (size_t)s * (CAN_N * CAN_D);

    // ================= phase 1: issue ALL global loads =================
    // W (B-frag layout: lane holds W[k=quad*8+j][n], quads 0-1; 2-3 zero)
    float t0[8], t1[8];
    if (quad < 2) {
        const float* W0 = P + quad * 8 * CAN_D + n;
        const float* W1 = P + 272 + quad * 8 * CAN_D + n;
#pragma unroll
        for (int j = 0; j < 8; ++j) { t0[j] = W0[j * CAN_D]; t1[j] = W1[j * CAN_D]; }
    }
    const float b0v = P[256 + n];
    const float b1v = P[528 + n];

    // x rows for all 4 tiles: lane (quad<2, n) -> row t*16+n, 32B half quad.
    float4 xu0[4], xu1[4];
#pragma unroll
    for (int t = 0; t < 4; ++t) {
        if (quad < 2) {
            int row = t * 16 + n;
            if (row > CAN_N - 1) row = CAN_N - 1;  // clamp; masked at store
            const float4* px = (const float4*)(xbase + row * CAN_D + quad * 8);
            xu0[t] = px[0];
            xu1[t] = px[1];
        }
    }

    // ================= phase 2: pack to bf16 fragments =================
    ABFrag w0, w1;
    if (quad < 2) {
#pragma unroll
        for (int j = 0; j < 4; ++j) {
            w0.i[j] = pack2(t0[2 * j], t0[2 * j + 1]);
            w1.i[j] = pack2(t1[2 * j], t1[2 * j + 1]);
        }
    } else {
#pragma unroll
        for (int j = 0; j < 4; ++j) { w0.i[j] = 0; w1.i[j] = 0; }
    }

    ABFrag a0[4];
#pragma unroll
    for (int t = 0; t < 4; ++t) {
        if (quad < 2) {
            a0[t].i[0] = pack2(xu0[t].x, xu0[t].y);
            a0[t].i[1] = pack2(xu0[t].z, xu0[t].w);
            a0[t].i[2] = pack2(xu1[t].x, xu1[t].y);
            a0[t].i[3] = pack2(xu1[t].z, xu1[t].w);
        } else {
#pragma unroll
            for (int j = 0; j < 4; ++j) a0[t].i[j] = 0;
        }
    }

    // ================= phase 3: compute (ping-pong LDS) =================
#pragma unroll
    for (int t = 0; t < 4; ++t) {
        float* yb = &ybuf[wave][t & 1][0];

        f32x4 c0 = {b0v, b0v, b0v, b0v};
        c0 = __builtin_amdgcn_mfma_f32_16x16x32_bf16(a0[t].v, w0.v, c0, 0, 0, 0);

        // relu + C-layout -> LDS (row = quad*4+r, col = n)
#pragma unroll
        for (int r = 0; r < 4; ++r)
            yb[(quad * 4 + r) * YSTRIDE + n] = fmaxf(c0[r], 0.0f);

        // A-layout readback: lane (quad<2, n) reads y[n][quad*8 .. +7]
        ABFrag a1;
        if (quad < 2) {
            const float* pr = yb + n * YSTRIDE + quad * 8;   // 16B aligned
            float4 v0 = *(const float4*)pr;
            float4 v1 = *(const float4*)(pr + 4);
            a1.i[0] = pack2(v0.x, v0.y);
            a1.i[1] = pack2(v0.z, v0.w);
            a1.i[2] = pack2(v1.x, v1.y);
            a1.i[3] = pack2(v1.z, v1.w);
        } else {
#pragma unroll
            for (int j = 0; j < 4; ++j) a1.i[j] = 0;
        }

        f32x4 c1 = {b1v, b1v, b1v, b1v};
        c1 = __builtin_amdgcn_mfma_f32_16x16x32_bf16(a1.v, w1.v, c1, 0, 0, 0);

        // relu + transpose through the same buffer, then float4 store:
        // lane l stores row t*16 + (l>>2), floats (l&3)*4 .. +3.
#pragma unroll
        for (int r = 0; r < 4; ++r)
            yb[(quad * 4 + r) * YSTRIDE + n] = fmaxf(c1[r], 0.0f);

        const int srow = lane >> 2;
        const int scol = lane & 3;
        float4 ov = *(const float4*)(yb + srow * YSTRIDE + scol * 4);
        const int grow = t * 16 + srow;
        if (grow < CAN_N)
            *(float4*)(obase + grow * CAN_D + scol * 4) = ov;
    }
}

extern "C" void kernel_launch(void* const* d_in, const int* in_sizes, int n_in,
                              void* d_out, int out_size, void* d_ws, size_t ws_size,
                              hipStream_t stream) {
    const float* user_emb = (const float*)d_in[0];
    const float* item_emb = (const float*)d_in[1];
    float* out = (float*)d_out;

    const int B = in_sizes[0] / (CAN_N * CAN_D);   // 16384
    const int blocks = (B + WAVES_PER_BLOCK - 1) / WAVES_PER_BLOCK;
    can_kernel<<<blocks, 256, 0, stream>>>(user_emb, item_emb, out, B);
}

// Round 7
// 123.976 us; speedup vs baseline: 1.6027x; 1.0202x over previous
//
#include <hip/hip_runtime.h>

// CAN: per-sample 2-layer MLP, B=16384, N=50, D=16.
// R7 = R5's VERIFIED 16x16x32 MFMA math (absmax 0.5 pass) with ONLY the data
// path changed to global_load_lds staging (isolating R6's two variables):
//   - 7 DMA instr/wave stage x(3200B)+P(2176B) into wave-private LDS,
//     64x16B coalesced; tails width-4 with clamped per-lane addresses.
//   - __syncthreads() = vmcnt(0) drain (m97 pattern).
//   - Fragments then read from LDS: W strided ds_read_b32 (2-way bank = free),
//     A rows as 2x ds_read_b128.
//   - Inter-layer transpose ping-pongs inside the (now free) x stage.
//   - Direct C-layout dword stores (wave covers contiguous 1KB/tile; R2/R5
//     showed identical WRITE_SIZE for scattered vs vectorized).

#define CAN_D 16
#define CAN_N 50
#define CAN_PSTRIDE 544
#define WAVES_PER_BLOCK 4
#define XSTAGE 3328          // 3*1024 + 256B tail piece
#define PSTAGE 2304          // 2*1024 + 256B tail piece
#define SSTAGE (XSTAGE + PSTAGE)
#define YS 20                // ytr row stride (floats): 80B rows, 16B-aligned

typedef __attribute__((ext_vector_type(8))) short short8;   // 8 bf16
typedef __attribute__((ext_vector_type(4))) float f32x4;
#define AS1 __attribute__((address_space(1)))
#define AS3 __attribute__((address_space(3)))

union ABFrag { int i[4]; short8 v; };

// RNE fp32->bf16, lo -> bits [15:0]
__device__ __forceinline__ int pack2(float lo, float hi) {
    unsigned short ua = __builtin_bit_cast(unsigned short, (__bf16)lo);
    unsigned short ub = __builtin_bit_cast(unsigned short, (__bf16)hi);
    return (int)((unsigned)ua | ((unsigned)ub << 16));
}

__device__ __forceinline__ void dma16(const float* g, char* l) {
    __builtin_amdgcn_global_load_lds((const AS1 void*)g, (AS3 void*)l, 16, 0, 0);
}
__device__ __forceinline__ void dma4(const float* g, char* l) {
    __builtin_amdgcn_global_load_lds((const AS1 void*)g, (AS3 void*)l, 4, 0, 0);
}

__global__ __launch_bounds__(256, 5) void can_kernel(
    const float* __restrict__ user_emb,
    const float* __restrict__ item_emb,
    float* __restrict__ out, int B)
{
    __shared__ __align__(16) char smem[WAVES_PER_BLOCK * SSTAGE];

    const int wave = threadIdx.x >> 6;
    const int lane = threadIdx.x & 63;
    const int s = blockIdx.x * WAVES_PER_BLOCK + wave;
    const bool active = (s < B);

    char* xw = smem + wave * SSTAGE;
    char* pw = xw + XSTAGE;

    if (active) {
        const float* gx = user_emb + (size_t)s * (CAN_N * CAN_D); // 800 f
        const float* gp = item_emb + (size_t)s * CAN_PSTRIDE;     // 544 f
        dma16(gx +       lane * 4, xw);
        dma16(gx + 256 + lane * 4, xw + 1024);
        dma16(gx + 512 + lane * 4, xw + 2048);
        { int idx = 768 + lane; if (idx > 799) idx = 799;
          dma4(gx + idx, xw + 3072); }
        dma16(gp +       lane * 4, pw);
        dma16(gp + 256 + lane * 4, pw + 1024);
        { int idx = 512 + lane; if (idx > 543) idx = 543;
          dma4(gp + idx, pw + 2048); }
    }

    __syncthreads();    // drains vmcnt(0): DMA data visible in LDS
    if (!active) return;

    const int n    = lane & 15;     // MFMA col
    const int quad = lane >> 4;
    const float* pf = (const float*)pw;
    const float* xf = (const float*)xw;

    // ---- W/bias fragments (VERIFIED layout: lane holds W[k=quad*8+j][n],
    // quads 0-1; quads 2-3 -> k>=16 -> zero)
    ABFrag w0, w1;
    const float b0v = pf[256 + n];
    const float b1v = pf[528 + n];
    if (quad < 2) {
        float t0[8], t1[8];
#pragma unroll
        for (int j = 0; j < 8; ++j) {
            t0[j] = pf[(quad * 8 + j) * CAN_D + n];
            t1[j] = pf[272 + (quad * 8 + j) * CAN_D + n];
        }
#pragma unroll
        for (int j = 0; j < 4; ++j) {
            w0.i[j] = pack2(t0[2 * j], t0[2 * j + 1]);
            w1.i[j] = pack2(t1[2 * j], t1[2 * j + 1]);
        }
    } else {
#pragma unroll
        for (int j = 0; j < 4; ++j) { w0.i[j] = 0; w1.i[j] = 0; }
    }

    // ---- a0 fragments for all 4 tiles (read x stage BEFORE ytr reuses it)
    ABFrag a0[4];
#pragma unroll
    for (int t = 0; t < 4; ++t) {
        if (quad < 2) {
            int row = t * 16 + n;
            if (row > CAN_N - 1) row = CAN_N - 1;   // clamp; masked at store
            const float4* pr = (const float4*)(xf + row * CAN_D + quad * 8);
            float4 u0 = pr[0], u1 = pr[1];
            a0[t].i[0] = pack2(u0.x, u0.y);
            a0[t].i[1] = pack2(u0.z, u0.w);
            a0[t].i[2] = pack2(u1.x, u1.y);
            a0[t].i[3] = pack2(u1.z, u1.w);
        } else {
#pragma unroll
            for (int j = 0; j < 4; ++j) a0[t].i[j] = 0;
        }
    }

    float* ob = out + (size_t)s * (CAN_N * CAN_D);

#pragma unroll
    for (int t = 0; t < 4; ++t) {
        // ping-pong ytr inside the freed x stage (2 x 1280B <= 3328B)
        float* yt = (float*)(xw + (t & 1) * 1280);

        f32x4 c0 = {b0v, b0v, b0v, b0v};
        c0 = __builtin_amdgcn_mfma_f32_16x16x32_bf16(a0[t].v, w0.v, c0, 0, 0, 0);

        // relu + C-layout -> LDS (row = quad*4+r, col = n) [VERIFIED]
#pragma unroll
        for (int r = 0; r < 4; ++r)
            yt[(quad * 4 + r) * YS + n] = fmaxf(c0[r], 0.0f);

        // A-layout readback: lane (quad<2, n) reads y[n][quad*8 .. +7]
        ABFrag a1;
        if (quad < 2) {
            const float* pr = yt + n * YS + quad * 8;   // 16B aligned (YS=20)
            float4 v0 = *(const float4*)pr;
            float4 v1 = *(const float4*)(pr + 4);
            a1.i[0] = pack2(v0.x, v0.y);
            a1.i[1] = pack2(v0.z, v0.w);
            a1.i[2] = pack2(v1.x, v1.y);
            a1.i[3] = pack2(v1.z, v1.w);
        } else {
#pragma unroll
            for (int j = 0; j < 4; ++j) a1.i[j] = 0;
        }

        f32x4 c1 = {b1v, b1v, b1v, b1v};
        c1 = __builtin_amdgcn_mfma_f32_16x16x32_bf16(a1.v, w1.v, c1, 0, 0, 0);

        // relu + direct C-layout store (row = t*16 + quad*4 + r, col = n)
#pragma unroll
        for (int r = 0; r < 4; ++r) {
            int grow = t * 16 + quad * 4 + r;
            if (grow < CAN_N)
                ob[grow * CAN_D + n] = fmaxf(c1[r], 0.0f);
        }
    }
}

extern "C" void kernel_launch(void* const* d_in, const int* in_sizes, int n_in,
                              void* d_out, int out_size, void* d_ws, size_t ws_size,
                              hipStream_t stream) {
    const float* user_emb = (const float*)d_in[0];
    const float* item_emb = (const float*)d_in[1];
    float* out = (float*)d_out;

    const int B = in_sizes[0] / (CAN_N * CAN_D);   // 16384
    const int blocks = (B + WAVES_PER_BLOCK - 1) / WAVES_PER_BLOCK;
    can_kernel<<<blocks, 256, 0, stream>>>(user_emb, item_emb, out, B);
}